// Round 1
// baseline (1213.000 us; speedup 1.0000x reference)
//
#include <hip/hip_runtime.h>
#include <cstdint>
#include <cstddef>

#define N_NODES 100000
#define E_EDGES 1000000
#define IN_DIM  128
#define HID     256
#define NG      64
#define EPSV    1e-5f

// ---------------- ws layout (bytes) ----------------
// zeroed region [0, ZERO_BYTES)
static constexpr size_t OFF_DEG    = 0;          // N int
static constexpr size_t OFF_CNT    = 400128;     // 64 int
static constexpr size_t OFF_CSUM   = 400384;     // 256 f32
static constexpr size_t OFF_CSQ    = 401408;     // 256 f32
static constexpr size_t OFF_POOLR  = 402432;     // 64*256 f32
static constexpr size_t OFF_CSUM1  = 467968;     // 256 f32
static constexpr size_t OFF_CSQ1   = 468992;     // 256 f32
static constexpr size_t OFF_CSUM2  = 470016;     // 256 f32
static constexpr size_t OFF_CSQ2   = 471040;     // 256 f32
static constexpr size_t ZERO_BYTES = 472064;
// non-zeroed
static constexpr size_t OFF_ROWOFF = 472064;     // (N+1) int
static constexpr size_t OFF_CURSOR = 872320;     // N int
static constexpr size_t OFF_SSRC   = 1272448;    // E int
static constexpr size_t OFF_HN     = 5272448;    // N*128 f32
static constexpr size_t OFF_POOLF  = 56472448;   // 64*256 f32
static constexpr size_t OFF_Y1R    = 56537984;   // 64*256 f32
static constexpr size_t OFF_PBUF   = 56603520;   // 64*256 f32
static constexpr size_t OFF_Y2R    = 56669056;   // 64*256 f32

// -------- degree count + graph node count --------
__global__ void k_count(const int* __restrict__ dst, const int* __restrict__ gid,
                        int* __restrict__ deg, int* __restrict__ cnt) {
    int i = blockIdx.x * blockDim.x + threadIdx.x;
    int stride = gridDim.x * blockDim.x;
    for (int e = i; e < E_EDGES; e += stride) atomicAdd(&deg[dst[e]], 1);
    for (int n = i; n < N_NODES; n += stride) atomicAdd(&cnt[gid[n]], 1);
}

// -------- single-block exclusive scan of deg -> row_off, cursor --------
__global__ __launch_bounds__(256) void k_scan(const int* __restrict__ deg,
                                              int* __restrict__ row_off,
                                              int* __restrict__ cursor) {
    __shared__ int sums[256];
    int tid = threadIdx.x;
    int carry = 0;
    for (int t0 = 0; t0 < N_NODES; t0 += 4096) {
        int base = t0 + tid * 16;
        int v[16];
        int s = 0;
#pragma unroll
        for (int i = 0; i < 16; ++i) {
            int idx = base + i;
            v[i] = (idx < N_NODES) ? deg[idx] : 0;
            s += v[i];
        }
        sums[tid] = s;
        __syncthreads();
        // Hillis-Steele inclusive scan over 256
        for (int off = 1; off < 256; off <<= 1) {
            int add = (tid >= off) ? sums[tid - off] : 0;
            __syncthreads();
            sums[tid] += add;
            __syncthreads();
        }
        int run = carry + (tid ? sums[tid - 1] : 0);
#pragma unroll
        for (int i = 0; i < 16; ++i) {
            int idx = base + i;
            if (idx < N_NODES) { row_off[idx] = run; cursor[idx] = run; }
            run += v[i];
        }
        int total = carry + sums[255];
        __syncthreads();
        carry = total;
    }
    if (tid == 0) row_off[N_NODES] = carry;  // == E
}

// -------- scatter edges into CSR order --------
__global__ void k_scatter(const int* __restrict__ src, const int* __restrict__ dst,
                          int* __restrict__ cursor, int* __restrict__ sorted_src) {
    int i = blockIdx.x * blockDim.x + threadIdx.x;
    int stride = gridDim.x * blockDim.x;
    for (int e = i; e < E_EDGES; e += stride) {
        int d = dst[e];
        int pos = atomicAdd(&cursor[d], 1);
        sorted_src[pos] = src[e];
    }
}

// -------- mean aggregation: one wave per node --------
__global__ __launch_bounds__(256) void k_agg(const float* __restrict__ feat,
                                             const int* __restrict__ row_off,
                                             const int* __restrict__ sorted_src,
                                             float* __restrict__ h_neigh) {
    int wave = threadIdx.x >> 6;
    int lane = threadIdx.x & 63;
    int n = blockIdx.x * 4 + wave;
    if (n >= N_NODES) return;
    int k0 = __builtin_amdgcn_readfirstlane(row_off[n]);
    int k1 = __builtin_amdgcn_readfirstlane(row_off[n + 1]);
    float ax = 0.f, ay = 0.f;
    int k = k0;
    for (; k + 4 <= k1; k += 4) {
        int s0 = sorted_src[k], s1 = sorted_src[k + 1], s2 = sorted_src[k + 2], s3 = sorted_src[k + 3];
        float2 v0 = *reinterpret_cast<const float2*>(&feat[(size_t)s0 * IN_DIM + lane * 2]);
        float2 v1 = *reinterpret_cast<const float2*>(&feat[(size_t)s1 * IN_DIM + lane * 2]);
        float2 v2 = *reinterpret_cast<const float2*>(&feat[(size_t)s2 * IN_DIM + lane * 2]);
        float2 v3 = *reinterpret_cast<const float2*>(&feat[(size_t)s3 * IN_DIM + lane * 2]);
        ax += v0.x + v1.x + v2.x + v3.x;
        ay += v0.y + v1.y + v2.y + v3.y;
    }
    for (; k < k1; ++k) {
        int s0 = sorted_src[k];
        float2 v0 = *reinterpret_cast<const float2*>(&feat[(size_t)s0 * IN_DIM + lane * 2]);
        ax += v0.x; ay += v0.y;
    }
    float inv = 1.f / fmaxf((float)(k1 - k0), 1.f);
    *reinterpret_cast<float2*>(&h_neigh[(size_t)n * IN_DIM + lane * 2]) =
        make_float2(ax * inv, ay * inv);
}

// -------- fused conv GEMM + relu + BN stats + graph pooling --------
// h = feat@W_self + h_neigh@W_neigh + b_conv ; r = relu(h)
// colsum/colsq += column sums of r ; pooled_raw[g] += per-graph row sums of r
__global__ __launch_bounds__(256) void k_gemm(const float* __restrict__ feat,
                                              const float* __restrict__ h_neigh,
                                              const float* __restrict__ W_self,
                                              const float* __restrict__ W_neigh,
                                              const float* __restrict__ b_conv,
                                              const int* __restrict__ gid,
                                              float* __restrict__ colsum,
                                              float* __restrict__ colsq,
                                              float* __restrict__ pooled_raw) {
    __shared__ __align__(16) float A_l[32][72];   // [k][row]
    __shared__ __align__(16) float B_l[32][256];  // [k][col]
    __shared__ float csum_l[256], csq_l[256];
    __shared__ float pool_l[4][256];
    __shared__ int gid_l[64];

    int tid = threadIdx.x;
    int n0 = blockIdx.x * 64;
    csum_l[tid] = 0.f; csq_l[tid] = 0.f;
#pragma unroll
    for (int s = 0; s < 4; ++s) pool_l[s][tid] = 0.f;
    if (tid < 64) gid_l[tid] = (n0 + tid < N_NODES) ? gid[n0 + tid] : 0x7fffffff;
    __syncthreads();

    int ty = tid >> 5;   // 0..7  -> rows ty*8 .. ty*8+7
    int tx = tid & 31;   // 0..31 -> cols tx*8 .. tx*8+7
    float acc[8][8];
#pragma unroll
    for (int i = 0; i < 8; ++i)
#pragma unroll
        for (int j = 0; j < 8; ++j) acc[i][j] = 0.f;

    for (int kc = 0; kc < 8; ++kc) {
        int k0 = kc * 32;
        const float* Asrc = (k0 < 128) ? feat : h_neigh;
        int ak0 = (k0 < 128) ? k0 : k0 - 128;
        const float* Bsrc = (k0 < 128) ? W_self : W_neigh;

        // A tile: 64 rows x 32 k, transposed into LDS
#pragma unroll
        for (int t = 0; t < 2; ++t) {
            int idx = t * 256 + tid;      // 0..511
            int r = idx & 63;
            int c4 = (idx >> 6) * 4;      // 0,4,..,28
            int n = n0 + r;
            float4 v = make_float4(0.f, 0.f, 0.f, 0.f);
            if (n < N_NODES)
                v = *reinterpret_cast<const float4*>(&Asrc[(size_t)n * IN_DIM + ak0 + c4]);
            A_l[c4 + 0][r] = v.x; A_l[c4 + 1][r] = v.y;
            A_l[c4 + 2][r] = v.z; A_l[c4 + 3][r] = v.w;
        }
        // B tile: 32 k x 256 cols, direct
#pragma unroll
        for (int t = 0; t < 8; ++t) {
            int idx = t * 256 + tid;      // 0..2047
            int r = idx >> 6;             // k row 0..31
            int c4 = (idx & 63) * 4;
            float4 v = *reinterpret_cast<const float4*>(&Bsrc[(size_t)r * HID + (size_t)k0 * 0 + c4 + (size_t)0]);
            // note: Bsrc row index must include k-offset within the source matrix
            v = *reinterpret_cast<const float4*>(&Bsrc[((size_t)(((k0 < 128) ? k0 : k0 - 128) + r)) * HID + c4]);
            *reinterpret_cast<float4*>(&B_l[r][c4]) = v;
        }
        __syncthreads();

        for (int kb = 0; kb < 4; ++kb) {
#pragma unroll
            for (int u = 0; u < 8; ++u) {
                int kk = kb * 8 + u;
                float4 a0 = *reinterpret_cast<const float4*>(&A_l[kk][ty * 8]);
                float4 a1 = *reinterpret_cast<const float4*>(&A_l[kk][ty * 8 + 4]);
                float4 b0 = *reinterpret_cast<const float4*>(&B_l[kk][tx * 8]);
                float4 b1 = *reinterpret_cast<const float4*>(&B_l[kk][tx * 8 + 4]);
                float av[8] = {a0.x, a0.y, a0.z, a0.w, a1.x, a1.y, a1.z, a1.w};
                float bv[8] = {b0.x, b0.y, b0.z, b0.w, b1.x, b1.y, b1.z, b1.w};
#pragma unroll
                for (int i = 0; i < 8; ++i)
#pragma unroll
                    for (int j = 0; j < 8; ++j)
                        acc[i][j] = fmaf(av[i], bv[j], acc[i][j]);
            }
        }
        __syncthreads();
    }

    // ---- epilogue: bias, relu, BN-stats, graph pooling ----
    float bc[8];
    {
        float4 t0 = *reinterpret_cast<const float4*>(&b_conv[tx * 8]);
        float4 t1 = *reinterpret_cast<const float4*>(&b_conv[tx * 8 + 4]);
        bc[0] = t0.x; bc[1] = t0.y; bc[2] = t0.z; bc[3] = t0.w;
        bc[4] = t1.x; bc[5] = t1.y; bc[6] = t1.z; bc[7] = t1.w;
    }
    float cs[8], cq[8], ps[8];
#pragma unroll
    for (int j = 0; j < 8; ++j) { cs[j] = 0.f; cq[j] = 0.f; ps[j] = 0.f; }
    int g_base = gid_l[0];
    int cur_g = -1;
#pragma unroll
    for (int i = 0; i < 8; ++i) {
        int n = n0 + ty * 8 + i;
        if (n < N_NODES) {
            int g = gid_l[ty * 8 + i];
            if (g != cur_g) {
                if (cur_g >= 0) {
                    int slot = cur_g - g_base;
                    if (slot < 4) {
#pragma unroll
                        for (int j = 0; j < 8; ++j)
                            if (ps[j] != 0.f) atomicAdd(&pool_l[slot][tx * 8 + j], ps[j]);
                    } else {
#pragma unroll
                        for (int j = 0; j < 8; ++j)
                            if (ps[j] != 0.f) atomicAdd(&pooled_raw[cur_g * HID + tx * 8 + j], ps[j]);
                    }
#pragma unroll
                    for (int j = 0; j < 8; ++j) ps[j] = 0.f;
                }
                cur_g = g;
            }
#pragma unroll
            for (int j = 0; j < 8; ++j) {
                float v = fmaxf(acc[i][j] + bc[j], 0.f);
                cs[j] += v; cq[j] += v * v; ps[j] += v;
            }
        }
    }
    if (cur_g >= 0) {
        int slot = cur_g - g_base;
        if (slot < 4) {
#pragma unroll
            for (int j = 0; j < 8; ++j)
                if (ps[j] != 0.f) atomicAdd(&pool_l[slot][tx * 8 + j], ps[j]);
        } else {
#pragma unroll
            for (int j = 0; j < 8; ++j)
                if (ps[j] != 0.f) atomicAdd(&pooled_raw[cur_g * HID + tx * 8 + j], ps[j]);
        }
    }
#pragma unroll
    for (int j = 0; j < 8; ++j) {
        atomicAdd(&csum_l[tx * 8 + j], cs[j]);
        atomicAdd(&csq_l[tx * 8 + j], cq[j]);
    }
    __syncthreads();
    atomicAdd(&colsum[tid], csum_l[tid]);
    atomicAdd(&colsq[tid], csq_l[tid]);
#pragma unroll
    for (int s = 0; s < 4; ++s) {
        int gg = g_base + s;
        if (gg < NG) {
            float v = pool_l[s][tid];
            if (v != 0.f) atomicAdd(&pooled_raw[gg * HID + tid], v);
        }
    }
}

// -------- finalize conv BN (affine on pooled sums) --------
__global__ void k_head_prep(const float* __restrict__ colsum, const float* __restrict__ colsq,
                            const float* __restrict__ gamma, const float* __restrict__ beta,
                            const int* __restrict__ cnt, const float* __restrict__ pooled_raw,
                            float* __restrict__ pooled_final) {
    int c = threadIdx.x;
    float mu = colsum[c] * (1.0f / N_NODES);
    float var = colsq[c] * (1.0f / N_NODES) - mu * mu;
    float a = gamma[c] * rsqrtf(var + EPSV);
    float off = beta[c] - a * mu;
    for (int g = 0; g < NG; ++g) {
        pooled_final[g * HID + c] = a * pooled_raw[g * HID + c] + (float)cnt[g] * off;
    }
}

// -------- lp linear: y = relu(x@W + b), accumulate BN stats --------
__global__ __launch_bounds__(256) void k_lp(const float* __restrict__ x,
                                            const float* __restrict__ W,
                                            const float* __restrict__ b,
                                            float* __restrict__ yrelu,
                                            float* __restrict__ csum,
                                            float* __restrict__ csq) {
    __shared__ float xl[256];
    int g = blockIdx.x, c = threadIdx.x;
    xl[c] = x[g * HID + c];
    __syncthreads();
    float acc = b[c];
#pragma unroll 8
    for (int k = 0; k < HID; ++k) acc = fmaf(xl[k], W[k * HID + c], acc);
    float r = fmaxf(acc, 0.f);
    yrelu[g * HID + c] = r;
    atomicAdd(&csum[c], r);
    atomicAdd(&csq[c], r * r);
}

// -------- apply BN (write p to ws and d_out) --------
__global__ void k_bn(const float* __restrict__ yrelu, const float* __restrict__ csum,
                     const float* __restrict__ csq, const float* __restrict__ gamma,
                     const float* __restrict__ beta, float* __restrict__ out_a,
                     float* __restrict__ out_b) {
    int g = blockIdx.x, c = threadIdx.x;
    float mu = csum[c] * (1.f / NG);
    float var = csq[c] * (1.f / NG) - mu * mu;
    float a = gamma[c] * rsqrtf(var + EPSV);
    float v = (yrelu[g * HID + c] - mu) * a + beta[c];
    out_a[g * HID + c] = v;
    out_b[g * HID + c] = v;
}

// -------- apply BN + log_softmax --------
__global__ __launch_bounds__(256) void k_bnsm(const float* __restrict__ yrelu,
                                              const float* __restrict__ csum,
                                              const float* __restrict__ csq,
                                              const float* __restrict__ gamma,
                                              const float* __restrict__ beta,
                                              float* __restrict__ out) {
    __shared__ float red[256];
    int g = blockIdx.x, c = threadIdx.x;
    float mu = csum[c] * (1.f / NG);
    float var = csq[c] * (1.f / NG) - mu * mu;
    float a = gamma[c] * rsqrtf(var + EPSV);
    float z = (yrelu[g * HID + c] - mu) * a + beta[c];
    red[c] = z;
    __syncthreads();
    for (int s = 128; s > 0; s >>= 1) {
        if (c < s) red[c] = fmaxf(red[c], red[c + s]);
        __syncthreads();
    }
    float m = red[0];
    __syncthreads();
    red[c] = expf(z - m);
    __syncthreads();
    for (int s = 128; s > 0; s >>= 1) {
        if (c < s) red[c] += red[c + s];
        __syncthreads();
    }
    float lse = m + logf(red[0]);
    out[g * HID + c] = z - lse;
}

extern "C" void kernel_launch(void* const* d_in, const int* in_sizes, int n_in,
                              void* d_out, int out_size, void* d_ws, size_t ws_size,
                              hipStream_t stream) {
    const float* feat    = (const float*)d_in[0];
    const float* W_self  = (const float*)d_in[1];
    const float* W_neigh = (const float*)d_in[2];
    const float* b_conv  = (const float*)d_in[3];
    const float* g_conv  = (const float*)d_in[4];
    const float* be_conv = (const float*)d_in[5];
    const float* W_lp    = (const float*)d_in[6];
    const float* b_lp    = (const float*)d_in[7];
    const float* g_lp    = (const float*)d_in[8];
    const float* be_lp   = (const float*)d_in[9];
    const int* src = (const int*)d_in[10];
    const int* dst = (const int*)d_in[11];
    const int* gid = (const int*)d_in[12];

    char* ws = (char*)d_ws;
    int*   deg        = (int*)(ws + OFF_DEG);
    int*   cnt        = (int*)(ws + OFF_CNT);
    float* colsum     = (float*)(ws + OFF_CSUM);
    float* colsq      = (float*)(ws + OFF_CSQ);
    float* pooled_raw = (float*)(ws + OFF_POOLR);
    float* csum1      = (float*)(ws + OFF_CSUM1);
    float* csq1       = (float*)(ws + OFF_CSQ1);
    float* csum2      = (float*)(ws + OFF_CSUM2);
    float* csq2       = (float*)(ws + OFF_CSQ2);
    int*   row_off    = (int*)(ws + OFF_ROWOFF);
    int*   cursor     = (int*)(ws + OFF_CURSOR);
    int*   sorted_src = (int*)(ws + OFF_SSRC);
    float* h_neigh    = (float*)(ws + OFF_HN);
    float* pooled_f   = (float*)(ws + OFF_POOLF);
    float* y1r        = (float*)(ws + OFF_Y1R);
    float* p_buf      = (float*)(ws + OFF_PBUF);
    float* y2r        = (float*)(ws + OFF_Y2R);

    float* out_ls = (float*)d_out;             // [64,256] log_softmax
    float* out_p  = out_ls + NG * HID;         // [64,256] p

    hipMemsetAsync(d_ws, 0, ZERO_BYTES, stream);
    k_count<<<1024, 256, 0, stream>>>(dst, gid, deg, cnt);
    k_scan<<<1, 256, 0, stream>>>(deg, row_off, cursor);
    k_scatter<<<1024, 256, 0, stream>>>(src, dst, cursor, sorted_src);
    k_agg<<<25000, 256, 0, stream>>>(feat, row_off, sorted_src, h_neigh);
    k_gemm<<<1563, 256, 0, stream>>>(feat, h_neigh, W_self, W_neigh, b_conv, gid,
                                     colsum, colsq, pooled_raw);
    k_head_prep<<<1, 256, 0, stream>>>(colsum, colsq, g_conv, be_conv, cnt,
                                       pooled_raw, pooled_f);
    k_lp<<<NG, 256, 0, stream>>>(pooled_f, W_lp, b_lp, y1r, csum1, csq1);
    k_bn<<<NG, 256, 0, stream>>>(y1r, csum1, csq1, g_lp, be_lp, p_buf, out_p);
    k_lp<<<NG, 256, 0, stream>>>(p_buf, W_lp, b_lp, y2r, csum2, csq2);
    k_bnsm<<<NG, 256, 0, stream>>>(y2r, csum2, csq2, g_lp, be_lp, out_ls);
}

// Round 2
// 714.753 us; speedup vs baseline: 1.6971x; 1.6971x over previous
//
#include <hip/hip_runtime.h>
#include <cstdint>
#include <cstddef>

#define N_NODES 100000
#define E_EDGES 1000000
#define IN_DIM  128
#define HID     256
#define NG      64
#define EPSV    1e-5f

// ---------------- ws layout (bytes) ----------------
// zeroed region [0, ZERO_BYTES)
static constexpr size_t OFF_DEG    = 0;          // N int  (reused as start[65] after k_scan)
static constexpr size_t OFF_CSUM   = 400384;     // 256 f32
static constexpr size_t OFF_CSQ    = 401408;     // 256 f32
static constexpr size_t OFF_POOLR  = 402432;     // 64*256 f32
static constexpr size_t OFF_CSUM1  = 467968;     // 256 f32
static constexpr size_t OFF_CSQ1   = 468992;     // 256 f32
static constexpr size_t OFF_CSUM2  = 470016;     // 256 f32
static constexpr size_t OFF_CSQ2   = 471040;     // 256 f32
static constexpr size_t ZERO_BYTES = 472064;
// non-zeroed
static constexpr size_t OFF_ROWOFF = 472064;     // (N+1) int
static constexpr size_t OFF_CURSOR = 872320;     // N int
static constexpr size_t OFF_SSRC   = 1272448;    // E int
static constexpr size_t OFF_HN     = 5272448;    // N*128 f32
static constexpr size_t OFF_POOLF  = 56472448;   // 64*256 f32
static constexpr size_t OFF_Y1R    = 56537984;   // 64*256 f32
static constexpr size_t OFF_PBUF   = 56603520;   // 64*256 f32
static constexpr size_t OFF_Y2R    = 56669056;   // 64*256 f32

// -------- degree count (scattered atomics, no hot-spot) --------
__global__ void k_count(const int* __restrict__ dst, int* __restrict__ deg) {
    int i = blockIdx.x * blockDim.x + threadIdx.x;
    int stride = gridDim.x * blockDim.x;
    for (int e = i; e < E_EDGES; e += stride) atomicAdd(&deg[dst[e]], 1);
}

// -------- graph segment boundaries (gid is sorted) --------
// start[g] = first node index n with gid[n] >= g ; start[NG] = N
__global__ void k_bounds(const int* __restrict__ gid, int* __restrict__ start) {
    int n = blockIdx.x * blockDim.x + threadIdx.x;
    if (n >= N_NODES) return;
    int b = gid[n];
    if (n == 0) {
        for (int g = 0; g <= b; ++g) start[g] = 0;
    } else {
        int a = gid[n - 1];
        for (int g = a + 1; g <= b; ++g) start[g] = n;
    }
    if (n == N_NODES - 1) {
        for (int g = b + 1; g <= NG; ++g) start[g] = N_NODES;
    }
}

// -------- single-block exclusive scan of deg -> row_off, cursor --------
__global__ __launch_bounds__(256) void k_scan(const int* __restrict__ deg,
                                              int* __restrict__ row_off,
                                              int* __restrict__ cursor) {
    __shared__ int sums[256];
    int tid = threadIdx.x;
    int carry = 0;
    for (int t0 = 0; t0 < N_NODES; t0 += 4096) {
        int base = t0 + tid * 16;
        int v[16];
        int s = 0;
#pragma unroll
        for (int i = 0; i < 16; ++i) {
            int idx = base + i;
            v[i] = (idx < N_NODES) ? deg[idx] : 0;
            s += v[i];
        }
        sums[tid] = s;
        __syncthreads();
        // Hillis-Steele inclusive scan over 256
        for (int off = 1; off < 256; off <<= 1) {
            int add = (tid >= off) ? sums[tid - off] : 0;
            __syncthreads();
            sums[tid] += add;
            __syncthreads();
        }
        int run = carry + (tid ? sums[tid - 1] : 0);
#pragma unroll
        for (int i = 0; i < 16; ++i) {
            int idx = base + i;
            if (idx < N_NODES) { row_off[idx] = run; cursor[idx] = run; }
            run += v[i];
        }
        int total = carry + sums[255];
        __syncthreads();
        carry = total;
    }
    if (tid == 0) row_off[N_NODES] = carry;  // == E
}

// -------- scatter edges into CSR order --------
__global__ void k_scatter(const int* __restrict__ src, const int* __restrict__ dst,
                          int* __restrict__ cursor, int* __restrict__ sorted_src) {
    int i = blockIdx.x * blockDim.x + threadIdx.x;
    int stride = gridDim.x * blockDim.x;
    for (int e = i; e < E_EDGES; e += stride) {
        int d = dst[e];
        int pos = atomicAdd(&cursor[d], 1);
        sorted_src[pos] = src[e];
    }
}

// -------- mean aggregation: one wave per node --------
__global__ __launch_bounds__(256) void k_agg(const float* __restrict__ feat,
                                             const int* __restrict__ row_off,
                                             const int* __restrict__ sorted_src,
                                             float* __restrict__ h_neigh) {
    int wave = threadIdx.x >> 6;
    int lane = threadIdx.x & 63;
    int n = blockIdx.x * 4 + wave;
    if (n >= N_NODES) return;
    int k0 = __builtin_amdgcn_readfirstlane(row_off[n]);
    int k1 = __builtin_amdgcn_readfirstlane(row_off[n + 1]);
    float ax = 0.f, ay = 0.f;
    int k = k0;
    for (; k + 4 <= k1; k += 4) {
        int s0 = sorted_src[k], s1 = sorted_src[k + 1], s2 = sorted_src[k + 2], s3 = sorted_src[k + 3];
        float2 v0 = *reinterpret_cast<const float2*>(&feat[(size_t)s0 * IN_DIM + lane * 2]);
        float2 v1 = *reinterpret_cast<const float2*>(&feat[(size_t)s1 * IN_DIM + lane * 2]);
        float2 v2 = *reinterpret_cast<const float2*>(&feat[(size_t)s2 * IN_DIM + lane * 2]);
        float2 v3 = *reinterpret_cast<const float2*>(&feat[(size_t)s3 * IN_DIM + lane * 2]);
        ax += v0.x + v1.x + v2.x + v3.x;
        ay += v0.y + v1.y + v2.y + v3.y;
    }
    for (; k < k1; ++k) {
        int s0 = sorted_src[k];
        float2 v0 = *reinterpret_cast<const float2*>(&feat[(size_t)s0 * IN_DIM + lane * 2]);
        ax += v0.x; ay += v0.y;
    }
    float inv = 1.f / fmaxf((float)(k1 - k0), 1.f);
    *reinterpret_cast<float2*>(&h_neigh[(size_t)n * IN_DIM + lane * 2]) =
        make_float2(ax * inv, ay * inv);
}

// -------- fused conv GEMM + relu + BN stats + graph pooling --------
// h = feat@W_self + h_neigh@W_neigh + b_conv ; r = relu(h)
// colsum/colsq += column sums of r ; pooled_raw[g] += per-graph row sums of r
__global__ __launch_bounds__(256) void k_gemm(const float* __restrict__ feat,
                                              const float* __restrict__ h_neigh,
                                              const float* __restrict__ W_self,
                                              const float* __restrict__ W_neigh,
                                              const float* __restrict__ b_conv,
                                              const int* __restrict__ gid,
                                              float* __restrict__ colsum,
                                              float* __restrict__ colsq,
                                              float* __restrict__ pooled_raw) {
    __shared__ __align__(16) float A_l[32][72];   // [k][row]
    __shared__ __align__(16) float B_l[32][256];  // [k][col]
    __shared__ float csum_l[256], csq_l[256];
    __shared__ float pool_l[4][256];
    __shared__ int gid_l[64];

    int tid = threadIdx.x;
    int n0 = blockIdx.x * 64;
    csum_l[tid] = 0.f; csq_l[tid] = 0.f;
#pragma unroll
    for (int s = 0; s < 4; ++s) pool_l[s][tid] = 0.f;
    if (tid < 64) gid_l[tid] = (n0 + tid < N_NODES) ? gid[n0 + tid] : 0x7fffffff;
    __syncthreads();

    int ty = tid >> 5;   // 0..7  -> rows ty*8 .. ty*8+7
    int tx = tid & 31;   // 0..31 -> cols tx*8 .. tx*8+7
    float acc[8][8];
#pragma unroll
    for (int i = 0; i < 8; ++i)
#pragma unroll
        for (int j = 0; j < 8; ++j) acc[i][j] = 0.f;

    for (int kc = 0; kc < 8; ++kc) {
        int k0 = kc * 32;
        const float* Asrc = (k0 < 128) ? feat : h_neigh;
        int ak0 = (k0 < 128) ? k0 : k0 - 128;
        const float* Bsrc = (k0 < 128) ? W_self : W_neigh;

        // A tile: 64 rows x 32 k, transposed into LDS
#pragma unroll
        for (int t = 0; t < 2; ++t) {
            int idx = t * 256 + tid;      // 0..511
            int r = idx & 63;
            int c4 = (idx >> 6) * 4;      // 0,4,..,28
            int n = n0 + r;
            float4 v = make_float4(0.f, 0.f, 0.f, 0.f);
            if (n < N_NODES)
                v = *reinterpret_cast<const float4*>(&Asrc[(size_t)n * IN_DIM + ak0 + c4]);
            A_l[c4 + 0][r] = v.x; A_l[c4 + 1][r] = v.y;
            A_l[c4 + 2][r] = v.z; A_l[c4 + 3][r] = v.w;
        }
        // B tile: 32 k x 256 cols, direct
#pragma unroll
        for (int t = 0; t < 8; ++t) {
            int idx = t * 256 + tid;      // 0..2047
            int r = idx >> 6;             // k row 0..31
            int c4 = (idx & 63) * 4;
            float4 v = *reinterpret_cast<const float4*>(&Bsrc[((size_t)(ak0 + r)) * HID + c4]);
            *reinterpret_cast<float4*>(&B_l[r][c4]) = v;
        }
        __syncthreads();

        for (int kb = 0; kb < 4; ++kb) {
#pragma unroll
            for (int u = 0; u < 8; ++u) {
                int kk = kb * 8 + u;
                float4 a0 = *reinterpret_cast<const float4*>(&A_l[kk][ty * 8]);
                float4 a1 = *reinterpret_cast<const float4*>(&A_l[kk][ty * 8 + 4]);
                float4 b0 = *reinterpret_cast<const float4*>(&B_l[kk][tx * 8]);
                float4 b1 = *reinterpret_cast<const float4*>(&B_l[kk][tx * 8 + 4]);
                float av[8] = {a0.x, a0.y, a0.z, a0.w, a1.x, a1.y, a1.z, a1.w};
                float bv[8] = {b0.x, b0.y, b0.z, b0.w, b1.x, b1.y, b1.z, b1.w};
#pragma unroll
                for (int i = 0; i < 8; ++i)
#pragma unroll
                    for (int j = 0; j < 8; ++j)
                        acc[i][j] = fmaf(av[i], bv[j], acc[i][j]);
            }
        }
        __syncthreads();
    }

    // ---- epilogue: bias, relu, BN-stats, graph pooling ----
    float bc[8];
    {
        float4 t0 = *reinterpret_cast<const float4*>(&b_conv[tx * 8]);
        float4 t1 = *reinterpret_cast<const float4*>(&b_conv[tx * 8 + 4]);
        bc[0] = t0.x; bc[1] = t0.y; bc[2] = t0.z; bc[3] = t0.w;
        bc[4] = t1.x; bc[5] = t1.y; bc[6] = t1.z; bc[7] = t1.w;
    }
    float cs[8], cq[8], ps[8];
#pragma unroll
    for (int j = 0; j < 8; ++j) { cs[j] = 0.f; cq[j] = 0.f; ps[j] = 0.f; }
    int g_base = gid_l[0];
    int cur_g = -1;
#pragma unroll
    for (int i = 0; i < 8; ++i) {
        int n = n0 + ty * 8 + i;
        if (n < N_NODES) {
            int g = gid_l[ty * 8 + i];
            if (g != cur_g) {
                if (cur_g >= 0) {
                    int slot = cur_g - g_base;
                    if (slot < 4) {
#pragma unroll
                        for (int j = 0; j < 8; ++j)
                            if (ps[j] != 0.f) atomicAdd(&pool_l[slot][tx * 8 + j], ps[j]);
                    } else {
#pragma unroll
                        for (int j = 0; j < 8; ++j)
                            if (ps[j] != 0.f) atomicAdd(&pooled_raw[cur_g * HID + tx * 8 + j], ps[j]);
                    }
#pragma unroll
                    for (int j = 0; j < 8; ++j) ps[j] = 0.f;
                }
                cur_g = g;
            }
#pragma unroll
            for (int j = 0; j < 8; ++j) {
                float v = fmaxf(acc[i][j] + bc[j], 0.f);
                cs[j] += v; cq[j] += v * v; ps[j] += v;
            }
        }
    }
    if (cur_g >= 0) {
        int slot = cur_g - g_base;
        if (slot < 4) {
#pragma unroll
            for (int j = 0; j < 8; ++j)
                if (ps[j] != 0.f) atomicAdd(&pool_l[slot][tx * 8 + j], ps[j]);
        } else {
#pragma unroll
            for (int j = 0; j < 8; ++j)
                if (ps[j] != 0.f) atomicAdd(&pooled_raw[cur_g * HID + tx * 8 + j], ps[j]);
        }
    }
#pragma unroll
    for (int j = 0; j < 8; ++j) {
        atomicAdd(&csum_l[tx * 8 + j], cs[j]);
        atomicAdd(&csq_l[tx * 8 + j], cq[j]);
    }
    __syncthreads();
    atomicAdd(&colsum[tid], csum_l[tid]);
    atomicAdd(&colsq[tid], csq_l[tid]);
#pragma unroll
    for (int s = 0; s < 4; ++s) {
        int gg = g_base + s;
        if (gg < NG) {
            float v = pool_l[s][tid];
            if (v != 0.f) atomicAdd(&pooled_raw[gg * HID + tid], v);
        }
    }
}

// -------- finalize conv BN (affine on pooled sums) --------
__global__ void k_head_prep(const float* __restrict__ colsum, const float* __restrict__ colsq,
                            const float* __restrict__ gamma, const float* __restrict__ beta,
                            const int* __restrict__ start, const float* __restrict__ pooled_raw,
                            float* __restrict__ pooled_final) {
    int c = threadIdx.x;
    float mu = colsum[c] * (1.0f / N_NODES);
    float var = colsq[c] * (1.0f / N_NODES) - mu * mu;
    float a = gamma[c] * rsqrtf(var + EPSV);
    float off = beta[c] - a * mu;
    for (int g = 0; g < NG; ++g) {
        float cg = (float)(start[g + 1] - start[g]);
        pooled_final[g * HID + c] = a * pooled_raw[g * HID + c] + cg * off;
    }
}

// -------- lp linear: y = relu(x@W + b), accumulate BN stats --------
__global__ __launch_bounds__(256) void k_lp(const float* __restrict__ x,
                                            const float* __restrict__ W,
                                            const float* __restrict__ b,
                                            float* __restrict__ yrelu,
                                            float* __restrict__ csum,
                                            float* __restrict__ csq) {
    __shared__ float xl[256];
    int g = blockIdx.x, c = threadIdx.x;
    xl[c] = x[g * HID + c];
    __syncthreads();
    float acc = b[c];
#pragma unroll 8
    for (int k = 0; k < HID; ++k) acc = fmaf(xl[k], W[k * HID + c], acc);
    float r = fmaxf(acc, 0.f);
    yrelu[g * HID + c] = r;
    atomicAdd(&csum[c], r);
    atomicAdd(&csq[c], r * r);
}

// -------- apply BN (write p to ws and d_out) --------
__global__ void k_bn(const float* __restrict__ yrelu, const float* __restrict__ csum,
                     const float* __restrict__ csq, const float* __restrict__ gamma,
                     const float* __restrict__ beta, float* __restrict__ out_a,
                     float* __restrict__ out_b) {
    int g = blockIdx.x, c = threadIdx.x;
    float mu = csum[c] * (1.f / NG);
    float var = csq[c] * (1.f / NG) - mu * mu;
    float a = gamma[c] * rsqrtf(var + EPSV);
    float v = (yrelu[g * HID + c] - mu) * a + beta[c];
    out_a[g * HID + c] = v;
    out_b[g * HID + c] = v;
}

// -------- apply BN + log_softmax --------
__global__ __launch_bounds__(256) void k_bnsm(const float* __restrict__ yrelu,
                                              const float* __restrict__ csum,
                                              const float* __restrict__ csq,
                                              const float* __restrict__ gamma,
                                              const float* __restrict__ beta,
                                              float* __restrict__ out) {
    __shared__ float red[256];
    int g = blockIdx.x, c = threadIdx.x;
    float mu = csum[c] * (1.f / NG);
    float var = csq[c] * (1.f / NG) - mu * mu;
    float a = gamma[c] * rsqrtf(var + EPSV);
    float z = (yrelu[g * HID + c] - mu) * a + beta[c];
    red[c] = z;
    __syncthreads();
    for (int s = 128; s > 0; s >>= 1) {
        if (c < s) red[c] = fmaxf(red[c], red[c + s]);
        __syncthreads();
    }
    float m = red[0];
    __syncthreads();
    red[c] = expf(z - m);
    __syncthreads();
    for (int s = 128; s > 0; s >>= 1) {
        if (c < s) red[c] += red[c + s];
        __syncthreads();
    }
    float lse = m + logf(red[0]);
    out[g * HID + c] = z - lse;
}

extern "C" void kernel_launch(void* const* d_in, const int* in_sizes, int n_in,
                              void* d_out, int out_size, void* d_ws, size_t ws_size,
                              hipStream_t stream) {
    const float* feat    = (const float*)d_in[0];
    const float* W_self  = (const float*)d_in[1];
    const float* W_neigh = (const float*)d_in[2];
    const float* b_conv  = (const float*)d_in[3];
    const float* g_conv  = (const float*)d_in[4];
    const float* be_conv = (const float*)d_in[5];
    const float* W_lp    = (const float*)d_in[6];
    const float* b_lp    = (const float*)d_in[7];
    const float* g_lp    = (const float*)d_in[8];
    const float* be_lp   = (const float*)d_in[9];
    const int* src = (const int*)d_in[10];
    const int* dst = (const int*)d_in[11];
    const int* gid = (const int*)d_in[12];

    char* ws = (char*)d_ws;
    int*   deg        = (int*)(ws + OFF_DEG);
    int*   start      = (int*)(ws + OFF_DEG);   // aliases deg; written after k_scan
    float* colsum     = (float*)(ws + OFF_CSUM);
    float* colsq      = (float*)(ws + OFF_CSQ);
    float* pooled_raw = (float*)(ws + OFF_POOLR);
    float* csum1      = (float*)(ws + OFF_CSUM1);
    float* csq1       = (float*)(ws + OFF_CSQ1);
    float* csum2      = (float*)(ws + OFF_CSUM2);
    float* csq2       = (float*)(ws + OFF_CSQ2);
    int*   row_off    = (int*)(ws + OFF_ROWOFF);
    int*   cursor     = (int*)(ws + OFF_CURSOR);
    int*   sorted_src = (int*)(ws + OFF_SSRC);
    float* h_neigh    = (float*)(ws + OFF_HN);
    float* pooled_f   = (float*)(ws + OFF_POOLF);
    float* y1r        = (float*)(ws + OFF_Y1R);
    float* p_buf      = (float*)(ws + OFF_PBUF);
    float* y2r        = (float*)(ws + OFF_Y2R);

    float* out_ls = (float*)d_out;             // [64,256] log_softmax
    float* out_p  = out_ls + NG * HID;         // [64,256] p

    hipMemsetAsync(d_ws, 0, ZERO_BYTES, stream);
    k_count<<<1024, 256, 0, stream>>>(dst, deg);
    k_scan<<<1, 256, 0, stream>>>(deg, row_off, cursor);
    k_bounds<<<(N_NODES + 255) / 256, 256, 0, stream>>>(gid, start);  // overwrites deg region (dead)
    k_scatter<<<1024, 256, 0, stream>>>(src, dst, cursor, sorted_src);
    k_agg<<<25000, 256, 0, stream>>>(feat, row_off, sorted_src, h_neigh);
    k_gemm<<<1563, 256, 0, stream>>>(feat, h_neigh, W_self, W_neigh, b_conv, gid,
                                     colsum, colsq, pooled_raw);
    k_head_prep<<<1, 256, 0, stream>>>(colsum, colsq, g_conv, be_conv, start,
                                       pooled_raw, pooled_f);
    k_lp<<<NG, 256, 0, stream>>>(pooled_f, W_lp, b_lp, y1r, csum1, csq1);
    k_bn<<<NG, 256, 0, stream>>>(y1r, csum1, csq1, g_lp, be_lp, p_buf, out_p);
    k_lp<<<NG, 256, 0, stream>>>(p_buf, W_lp, b_lp, y2r, csum2, csq2);
    k_bnsm<<<NG, 256, 0, stream>>>(y2r, csum2, csq2, g_lp, be_lp, out_ls);
}

// Round 3
// 415.782 us; speedup vs baseline: 2.9174x; 1.7191x over previous
//
#include <hip/hip_runtime.h>
#include <cstdint>
#include <cstddef>

#define N_NODES 100000
#define E_EDGES 1000000
#define IN_DIM  128
#define HID     256
#define NG      64
#define EPSV    1e-5f
#define NBLK    391        // ceil(N/256)

typedef float f32x4 __attribute__((ext_vector_type(4)));
typedef __bf16 bf16x8 __attribute__((ext_vector_type(8)));
typedef unsigned short ushort8 __attribute__((ext_vector_type(8)));

// ---------------- ws layout (bytes) ----------------
// zeroed region [0, ZERO_BYTES)
static constexpr size_t OFF_DEG    = 0;          // N int (later aliased as start[65])
static constexpr size_t OFF_CSUM   = 400000;     // 256 f32
static constexpr size_t OFF_CSQ    = 401024;     // 256 f32
static constexpr size_t OFF_POOLR  = 402048;     // 64*256 f32
static constexpr size_t OFF_CSUM1  = 467584;
static constexpr size_t OFF_CSQ1   = 468608;
static constexpr size_t OFF_CSUM2  = 469632;
static constexpr size_t OFF_CSQ2   = 470656;
static constexpr size_t ZERO_BYTES = 471680;
// non-zeroed
static constexpr size_t OFF_BSUM   = 471680;     // NBLK int
static constexpr size_t OFF_ROWOFF = 473728;     // (N+1) int
static constexpr size_t OFF_CURSOR = 873856;     // N int -- dead after k_scatter; aliased:
static constexpr size_t OFF_POOLF  = 873856;     //   64*256 f32
static constexpr size_t OFF_Y1R    = 939392;     //   64*256 f32
static constexpr size_t OFF_PBUF   = 1004928;    //   64*256 f32
static constexpr size_t OFF_Y2R    = 1070464;    //   64*256 f32
static constexpr size_t OFF_WT     = 1136000;    //   256*256 bf16 (128 KiB)
static constexpr size_t OFF_SSRC   = 1273856;    // E int
static constexpr size_t OFF_FB16   = 5273856;    // N*128 bf16
static constexpr size_t OFF_HN16   = 30873856;   // N*128 bf16  (end 56,473,856)

__device__ __forceinline__ unsigned short f2bf(float f) {
    union { float f; unsigned u; } x; x.f = f;
    unsigned r = x.u + 0x7FFFu + ((x.u >> 16) & 1u);
    return (unsigned short)(r >> 16);
}
__device__ __forceinline__ float bf2f(unsigned short h) {
    union { unsigned u; float f; } x; x.u = ((unsigned)h) << 16;
    return x.f;
}

// -------- degree count --------
__global__ void k_count(const int* __restrict__ dst, int* __restrict__ deg) {
    int i = blockIdx.x * blockDim.x + threadIdx.x;
    int stride = gridDim.x * blockDim.x;
    for (int e = i; e < E_EDGES; e += stride) atomicAdd(&deg[dst[e]], 1);
}

// -------- hierarchical scan: block sums --------
__global__ __launch_bounds__(256) void k_scan1(const int* __restrict__ deg, int* __restrict__ bsum) {
    __shared__ int sh[256];
    int b = blockIdx.x, t = threadIdx.x;
    int n = b * 256 + t;
    sh[t] = (n < N_NODES) ? deg[n] : 0;
    __syncthreads();
    for (int s = 128; s > 0; s >>= 1) {
        if (t < s) sh[t] += sh[t + s];
        __syncthreads();
    }
    if (t == 0) bsum[b] = sh[0];
}

// -------- scan of block sums (exclusive, in place) --------
__global__ __launch_bounds__(512) void k_scan2(int* __restrict__ bsum, int* __restrict__ row_off) {
    __shared__ int sh[512];
    int t = threadIdx.x;
    int v = (t < NBLK) ? bsum[t] : 0;
    sh[t] = v;
    __syncthreads();
    for (int off = 1; off < 512; off <<= 1) {
        int add = (t >= off) ? sh[t - off] : 0;
        __syncthreads();
        sh[t] += add;
        __syncthreads();
    }
    if (t < NBLK) bsum[t] = sh[t] - v;  // exclusive block offset
    if (t == 0) row_off[N_NODES] = E_EDGES;
}

// -------- per-block exclusive scan + offset --------
__global__ __launch_bounds__(256) void k_scan3(const int* __restrict__ deg, const int* __restrict__ bsum,
                                               int* __restrict__ row_off, int* __restrict__ cursor) {
    __shared__ int sh[256];
    int b = blockIdx.x, t = threadIdx.x;
    int n = b * 256 + t;
    int v = (n < N_NODES) ? deg[n] : 0;
    sh[t] = v;
    __syncthreads();
    for (int off = 1; off < 256; off <<= 1) {
        int add = (t >= off) ? sh[t - off] : 0;
        __syncthreads();
        sh[t] += add;
        __syncthreads();
    }
    int ex = bsum[b] + sh[t] - v;
    if (n < N_NODES) { row_off[n] = ex; cursor[n] = ex; }
}

// -------- graph segment boundaries (gid sorted) --------
__global__ void k_bounds(const int* __restrict__ gid, int* __restrict__ start) {
    int n = blockIdx.x * blockDim.x + threadIdx.x;
    if (n >= N_NODES) return;
    int b = gid[n];
    if (n == 0) {
        for (int g = 0; g <= b; ++g) start[g] = 0;
    } else {
        int a = gid[n - 1];
        for (int g = a + 1; g <= b; ++g) start[g] = n;
    }
    if (n == N_NODES - 1) {
        for (int g = b + 1; g <= NG; ++g) start[g] = N_NODES;
    }
}

// -------- scatter edges into CSR order --------
__global__ void k_scatter(const int* __restrict__ src, const int* __restrict__ dst,
                          int* __restrict__ cursor, int* __restrict__ sorted_src) {
    int i = blockIdx.x * blockDim.x + threadIdx.x;
    int stride = gridDim.x * blockDim.x;
    for (int e = i; e < E_EDGES; e += stride) {
        int d = dst[e];
        int pos = atomicAdd(&cursor[d], 1);
        sorted_src[pos] = src[e];
    }
}

// -------- feat f32 -> bf16 --------
__global__ __launch_bounds__(256) void k_cvt(const float* __restrict__ feat,
                                             unsigned short* __restrict__ fb) {
    int i = blockIdx.x * blockDim.x + threadIdx.x;   // 1.6M groups of 8
    const float4* f4 = (const float4*)feat;
    float4 a = f4[i * 2], b = f4[i * 2 + 1];
    ushort8 v;
    v[0] = f2bf(a.x); v[1] = f2bf(a.y); v[2] = f2bf(a.z); v[3] = f2bf(a.w);
    v[4] = f2bf(b.x); v[5] = f2bf(b.y); v[6] = f2bf(b.z); v[7] = f2bf(b.w);
    *(ushort8*)&fb[(size_t)i * 8] = v;
}

// -------- weight prepack: Wt[n][k] bf16, k<128 = W_self, else W_neigh --------
__global__ __launch_bounds__(256) void k_prepw(const float* __restrict__ W_self,
                                               const float* __restrict__ W_neigh,
                                               unsigned short* __restrict__ Wt) {
    int n = blockIdx.x, k = threadIdx.x;
    float w = (k < 128) ? W_self[k * HID + n] : W_neigh[(k - 128) * HID + n];
    Wt[n * 256 + k] = f2bf(w);
}

// -------- mean aggregation (bf16 gather, bf16 out): one wave per node --------
__global__ __launch_bounds__(256) void k_agg(const unsigned short* __restrict__ fb,
                                             const int* __restrict__ row_off,
                                             const int* __restrict__ sorted_src,
                                             unsigned short* __restrict__ hb) {
    int wave = threadIdx.x >> 6;
    int lane = threadIdx.x & 63;
    int n = blockIdx.x * 4 + wave;
    if (n >= N_NODES) return;
    int k0 = __builtin_amdgcn_readfirstlane(row_off[n]);
    int k1 = __builtin_amdgcn_readfirstlane(row_off[n + 1]);
    float ax = 0.f, ay = 0.f;
    int k = k0;
    for (; k + 4 <= k1; k += 4) {
        int s0 = sorted_src[k], s1 = sorted_src[k + 1], s2 = sorted_src[k + 2], s3 = sorted_src[k + 3];
        unsigned u0 = *(const unsigned*)&fb[(size_t)s0 * IN_DIM + lane * 2];
        unsigned u1 = *(const unsigned*)&fb[(size_t)s1 * IN_DIM + lane * 2];
        unsigned u2 = *(const unsigned*)&fb[(size_t)s2 * IN_DIM + lane * 2];
        unsigned u3 = *(const unsigned*)&fb[(size_t)s3 * IN_DIM + lane * 2];
        ax += bf2f(u0 & 0xffff) + bf2f(u1 & 0xffff) + bf2f(u2 & 0xffff) + bf2f(u3 & 0xffff);
        ay += bf2f(u0 >> 16) + bf2f(u1 >> 16) + bf2f(u2 >> 16) + bf2f(u3 >> 16);
    }
    for (; k < k1; ++k) {
        unsigned u0 = *(const unsigned*)&fb[(size_t)sorted_src[k] * IN_DIM + lane * 2];
        ax += bf2f(u0 & 0xffff);
        ay += bf2f(u0 >> 16);
    }
    float inv = 1.f / fmaxf((float)(k1 - k0), 1.f);
    unsigned out = (unsigned)f2bf(ax * inv) | ((unsigned)f2bf(ay * inv) << 16);
    *(unsigned*)&hb[(size_t)n * IN_DIM + lane * 2] = out;
}

// -------- MFMA conv GEMM + relu + BN stats + graph pooling --------
// block: 64 rows x 256 cols, 4 waves (each 32 rows x 128 cols)
__global__ __launch_bounds__(256) void k_gemm(const unsigned short* __restrict__ fb,
                                              const unsigned short* __restrict__ hb,
                                              const unsigned short* __restrict__ Wt,
                                              const float* __restrict__ b_conv,
                                              const int* __restrict__ gid,
                                              float* __restrict__ colsum,
                                              float* __restrict__ colsq,
                                              float* __restrict__ pooled_raw) {
    __shared__ unsigned short A_l[64 * 136];   // [row][k 0..127], stride 136 (pad 8)
    __shared__ unsigned short B_l[256 * 40];   // [n][k 0..31],  stride 40 (pad 8)
    __shared__ float csum_l[256], csq_l[256];
    __shared__ float pool_l[4][256];
    __shared__ int gid_s[64];

    int tid = threadIdx.x;
    int lane = tid & 63;
    int wid = tid >> 6;
    int n0 = blockIdx.x * 64;
    int wr = (wid >> 1) * 32;      // wave row offset in block (0 / 32)
    int wc = (wid & 1) * 128;      // wave col offset (0 / 128)

    csum_l[tid] = 0.f; csq_l[tid] = 0.f;
#pragma unroll
    for (int s = 0; s < 4; ++s) pool_l[s][tid] = 0.f;
    if (tid < 64) gid_s[tid] = (n0 + tid < N_NODES) ? gid[n0 + tid] : 0x7fffffff;

    f32x4 acc[2][8];
#pragma unroll
    for (int i = 0; i < 2; ++i)
#pragma unroll
        for (int j = 0; j < 8; ++j) acc[i][j] = (f32x4)0.f;

    for (int half = 0; half < 2; ++half) {
        const unsigned short* Asrc = half ? hb : fb;
        __syncthreads();   // protect A_l / B_l rewrite
        // stage A half: 64 rows x 128 k (1024 x 16B chunks)
#pragma unroll
        for (int c = 0; c < 4; ++c) {
            int ci = c * 256 + tid;
            int r = ci >> 4, part = ci & 15;
            ushort8 v = {0, 0, 0, 0, 0, 0, 0, 0};
            if (n0 + r < N_NODES)
                v = *(const ushort8*)&Asrc[(size_t)(n0 + r) * IN_DIM + part * 8];
            *(ushort8*)&A_l[r * 136 + part * 8] = v;
        }
#pragma unroll
        for (int kc = 0; kc < 4; ++kc) {
            int k0 = half * 128 + kc * 32;
            __syncthreads();  // previous B reads done (also orders A staging)
            // stage B: 256 n x 32 k (1024 x 16B chunks)
#pragma unroll
            for (int c = 0; c < 4; ++c) {
                int ci = c * 256 + tid;
                int nr = ci >> 2, part = ci & 3;
                ushort8 v = *(const ushort8*)&Wt[nr * 256 + k0 + part * 8];
                *(ushort8*)&B_l[nr * 40 + part * 8] = v;
            }
            __syncthreads();
            // fragments
            int kq = (lane >> 4) * 8;   // k sub-offset per lane group
            bf16x8 a0 = *(const bf16x8*)&A_l[(wr + (lane & 15)) * 136 + kc * 32 + kq];
            bf16x8 a1 = *(const bf16x8*)&A_l[(wr + 16 + (lane & 15)) * 136 + kc * 32 + kq];
            bf16x8 bfr[8];
#pragma unroll
            for (int cf = 0; cf < 8; ++cf)
                bfr[cf] = *(const bf16x8*)&B_l[(wc + cf * 16 + (lane & 15)) * 40 + kq];
#pragma unroll
            for (int cf = 0; cf < 8; ++cf) {
                acc[0][cf] = __builtin_amdgcn_mfma_f32_16x16x32_bf16(a0, bfr[cf], acc[0][cf], 0, 0, 0);
                acc[1][cf] = __builtin_amdgcn_mfma_f32_16x16x32_bf16(a1, bfr[cf], acc[1][cf], 0, 0, 0);
            }
        }
    }

    // ---- epilogue: bias, relu, BN stats, graph pooling ----
    int g_base = gid_s[0];
#pragma unroll
    for (int cf = 0; cf < 8; ++cf) {
        int ncol = wc + cf * 16 + (lane & 15);
        float bc = b_conv[ncol];
        float cs = 0.f, cq = 0.f, ps = 0.f;
        int cg = -1;
#pragma unroll
        for (int rf = 0; rf < 2; ++rf) {
#pragma unroll
            for (int j = 0; j < 4; ++j) {
                int rl = wr + rf * 16 + ((lane >> 4) << 2) + j;
                if (n0 + rl < N_NODES) {
                    int g = gid_s[rl];
                    if (g != cg) {
                        if (cg >= 0 && ps != 0.f) {
                            int slot = cg - g_base;
                            if (slot < 4) atomicAdd(&pool_l[slot][ncol], ps);
                            else          atomicAdd(&pooled_raw[cg * HID + ncol], ps);
                        }
                        ps = 0.f; cg = g;
                    }
                    float v = fmaxf(acc[rf][cf][j] + bc, 0.f);
                    cs += v; cq += v * v; ps += v;
                }
            }
        }
        if (cg >= 0 && ps != 0.f) {
            int slot = cg - g_base;
            if (slot < 4) atomicAdd(&pool_l[slot][ncol], ps);
            else          atomicAdd(&pooled_raw[cg * HID + ncol], ps);
        }
        atomicAdd(&csum_l[ncol], cs);
        atomicAdd(&csq_l[ncol], cq);
    }
    __syncthreads();
    atomicAdd(&colsum[tid], csum_l[tid]);
    atomicAdd(&colsq[tid], csq_l[tid]);
#pragma unroll
    for (int s = 0; s < 4; ++s) {
        int gg = g_base + s;
        if (gg < NG) {
            float v = pool_l[s][tid];
            if (v != 0.f) atomicAdd(&pooled_raw[gg * HID + tid], v);
        }
    }
}

// -------- finalize conv BN (affine on pooled sums) --------
__global__ void k_head_prep(const float* __restrict__ colsum, const float* __restrict__ colsq,
                            const float* __restrict__ gamma, const float* __restrict__ beta,
                            const int* __restrict__ start, const float* __restrict__ pooled_raw,
                            float* __restrict__ pooled_final) {
    int c = threadIdx.x;
    float mu = colsum[c] * (1.0f / N_NODES);
    float var = colsq[c] * (1.0f / N_NODES) - mu * mu;
    float a = gamma[c] * rsqrtf(var + EPSV);
    float off = beta[c] - a * mu;
    for (int g = 0; g < NG; ++g) {
        float cg = (float)(start[g + 1] - start[g]);
        pooled_final[g * HID + c] = a * pooled_raw[g * HID + c] + cg * off;
    }
}

// -------- lp linear: y = relu(x@W + b), accumulate BN stats --------
__global__ __launch_bounds__(256) void k_lp(const float* __restrict__ x,
                                            const float* __restrict__ W,
                                            const float* __restrict__ b,
                                            float* __restrict__ yrelu,
                                            float* __restrict__ csum,
                                            float* __restrict__ csq) {
    __shared__ float xl[256];
    int g = blockIdx.x, c = threadIdx.x;
    xl[c] = x[g * HID + c];
    __syncthreads();
    float acc = b[c];
#pragma unroll 8
    for (int k = 0; k < HID; ++k) acc = fmaf(xl[k], W[k * HID + c], acc);
    float r = fmaxf(acc, 0.f);
    yrelu[g * HID + c] = r;
    atomicAdd(&csum[c], r);
    atomicAdd(&csq[c], r * r);
}

// -------- apply BN (write p to ws and d_out) --------
__global__ void k_bn(const float* __restrict__ yrelu, const float* __restrict__ csum,
                     const float* __restrict__ csq, const float* __restrict__ gamma,
                     const float* __restrict__ beta, float* __restrict__ out_a,
                     float* __restrict__ out_b) {
    int g = blockIdx.x, c = threadIdx.x;
    float mu = csum[c] * (1.f / NG);
    float var = csq[c] * (1.f / NG) - mu * mu;
    float a = gamma[c] * rsqrtf(var + EPSV);
    float v = (yrelu[g * HID + c] - mu) * a + beta[c];
    out_a[g * HID + c] = v;
    out_b[g * HID + c] = v;
}

// -------- apply BN + log_softmax --------
__global__ __launch_bounds__(256) void k_bnsm(const float* __restrict__ yrelu,
                                              const float* __restrict__ csum,
                                              const float* __restrict__ csq,
                                              const float* __restrict__ gamma,
                                              const float* __restrict__ beta,
                                              float* __restrict__ out) {
    __shared__ float red[256];
    int g = blockIdx.x, c = threadIdx.x;
    float mu = csum[c] * (1.f / NG);
    float var = csq[c] * (1.f / NG) - mu * mu;
    float a = gamma[c] * rsqrtf(var + EPSV);
    float z = (yrelu[g * HID + c] - mu) * a + beta[c];
    red[c] = z;
    __syncthreads();
    for (int s = 128; s > 0; s >>= 1) {
        if (c < s) red[c] = fmaxf(red[c], red[c + s]);
        __syncthreads();
    }
    float m = red[0];
    __syncthreads();
    red[c] = expf(z - m);
    __syncthreads();
    for (int s = 128; s > 0; s >>= 1) {
        if (c < s) red[c] += red[c + s];
        __syncthreads();
    }
    float lse = m + logf(red[0]);
    out[g * HID + c] = z - lse;
}

extern "C" void kernel_launch(void* const* d_in, const int* in_sizes, int n_in,
                              void* d_out, int out_size, void* d_ws, size_t ws_size,
                              hipStream_t stream) {
    const float* feat    = (const float*)d_in[0];
    const float* W_self  = (const float*)d_in[1];
    const float* W_neigh = (const float*)d_in[2];
    const float* b_conv  = (const float*)d_in[3];
    const float* g_conv  = (const float*)d_in[4];
    const float* be_conv = (const float*)d_in[5];
    const float* W_lp    = (const float*)d_in[6];
    const float* b_lp    = (const float*)d_in[7];
    const float* g_lp    = (const float*)d_in[8];
    const float* be_lp   = (const float*)d_in[9];
    const int* src = (const int*)d_in[10];
    const int* dst = (const int*)d_in[11];
    const int* gid = (const int*)d_in[12];

    char* ws = (char*)d_ws;
    int*   deg        = (int*)(ws + OFF_DEG);
    int*   start      = (int*)(ws + OFF_DEG);   // alias, written after scans
    float* colsum     = (float*)(ws + OFF_CSUM);
    float* colsq      = (float*)(ws + OFF_CSQ);
    float* pooled_raw = (float*)(ws + OFF_POOLR);
    float* csum1      = (float*)(ws + OFF_CSUM1);
    float* csq1       = (float*)(ws + OFF_CSQ1);
    float* csum2      = (float*)(ws + OFF_CSUM2);
    float* csq2       = (float*)(ws + OFF_CSQ2);
    int*   bsum       = (int*)(ws + OFF_BSUM);
    int*   row_off    = (int*)(ws + OFF_ROWOFF);
    int*   cursor     = (int*)(ws + OFF_CURSOR);
    float* pooled_f   = (float*)(ws + OFF_POOLF);
    float* y1r        = (float*)(ws + OFF_Y1R);
    float* p_buf      = (float*)(ws + OFF_PBUF);
    float* y2r        = (float*)(ws + OFF_Y2R);
    unsigned short* Wt = (unsigned short*)(ws + OFF_WT);
    int*   sorted_src = (int*)(ws + OFF_SSRC);
    unsigned short* fb = (unsigned short*)(ws + OFF_FB16);
    unsigned short* hb = (unsigned short*)(ws + OFF_HN16);

    float* out_ls = (float*)d_out;             // [64,256] log_softmax
    float* out_p  = out_ls + NG * HID;         // [64,256] p

    hipMemsetAsync(d_ws, 0, ZERO_BYTES, stream);
    k_count<<<1024, 256, 0, stream>>>(dst, deg);
    k_scan1<<<NBLK, 256, 0, stream>>>(deg, bsum);
    k_scan2<<<1, 512, 0, stream>>>(bsum, row_off);
    k_scan3<<<NBLK, 256, 0, stream>>>(deg, bsum, row_off, cursor);
    k_bounds<<<(N_NODES + 255) / 256, 256, 0, stream>>>(gid, start);  // deg now dead
    k_scatter<<<1024, 256, 0, stream>>>(src, dst, cursor, sorted_src);
    k_cvt<<<6250, 256, 0, stream>>>(feat, fb);
    k_prepw<<<256, 256, 0, stream>>>(W_self, W_neigh, Wt);            // cursor now dead
    k_agg<<<25000, 256, 0, stream>>>(fb, row_off, sorted_src, hb);
    k_gemm<<<1563, 256, 0, stream>>>(fb, hb, Wt, b_conv, gid, colsum, colsq, pooled_raw);
    k_head_prep<<<1, 256, 0, stream>>>(colsum, colsq, g_conv, be_conv, start,
                                       pooled_raw, pooled_f);
    k_lp<<<NG, 256, 0, stream>>>(pooled_f, W_lp, b_lp, y1r, csum1, csq1);
    k_bn<<<NG, 256, 0, stream>>>(y1r, csum1, csq1, g_lp, be_lp, p_buf, out_p);
    k_lp<<<NG, 256, 0, stream>>>(p_buf, W_lp, b_lp, y2r, csum2, csq2);
    k_bnsm<<<NG, 256, 0, stream>>>(y2r, csum2, csq2, g_lp, be_lp, out_ls);
}

// Round 4
// 359.792 us; speedup vs baseline: 3.3714x; 1.1556x over previous
//
#include <hip/hip_runtime.h>
#include <cstdint>
#include <cstddef>

#define N_NODES 100000
#define E_EDGES 1000000
#define IN_DIM  128
#define HID     256
#define NG      64
#define EPSV    1e-5f
#define NBLK    391        // ceil(N/256)

typedef float f32x4 __attribute__((ext_vector_type(4)));
typedef __bf16 bf16x8 __attribute__((ext_vector_type(8)));
typedef unsigned short ushort8 __attribute__((ext_vector_type(8)));

// ---------------- ws layout (bytes) ----------------
// zeroed region [0, ZERO_BYTES)
static constexpr size_t OFF_DEG    = 0;          // N int (aliased by Wt after k_scan3)
static constexpr size_t OFF_CSUM   = 400000;     // 256 f32
static constexpr size_t OFF_CSQ    = 401024;     // 256 f32
static constexpr size_t OFF_POOLR  = 402048;     // 64*256 f32
static constexpr size_t OFF_CSUM1  = 467584;
static constexpr size_t OFF_CSQ1   = 468608;
static constexpr size_t OFF_CSUM2  = 469632;
static constexpr size_t OFF_CSQ2   = 470656;
static constexpr size_t ZERO_BYTES = 471680;
// non-zeroed
static constexpr size_t OFF_BSUM   = 471680;     // NBLK int (1564 B)
static constexpr size_t OFF_START  = 473344;     // 65 int
static constexpr size_t OFF_ROWOFF = 473728;     // (N+1) int
static constexpr size_t OFF_CURSOR = 873856;     // N int -- dead after k_scatter; aliased:
static constexpr size_t OFF_POOLF  = 873856;     //   64*256 f32
static constexpr size_t OFF_Y1R    = 939392;     //   64*256 f32
static constexpr size_t OFF_PBUF   = 1004928;    //   64*256 f32
static constexpr size_t OFF_Y2R    = 1070464;    //   64*256 f32
static constexpr size_t OFF_SSRC   = 1273856;    // E int
static constexpr size_t OFF_FB16   = 5273856;    // N*128 bf16
static constexpr size_t OFF_HN16   = 30873856;   // N*128 bf16 (end 56,473,856)
static constexpr size_t OFF_WT     = 0;          // 256*256 bf16, aliases deg (dead after scan3)

__device__ __forceinline__ unsigned short f2bf(float f) {
    union { float f; unsigned u; } x; x.f = f;
    unsigned r = x.u + 0x7FFFu + ((x.u >> 16) & 1u);
    return (unsigned short)(r >> 16);
}
__device__ __forceinline__ float bf2f(unsigned short h) {
    union { unsigned u; float f; } x; x.u = ((unsigned)h) << 16;
    return x.f;
}

// -------- fused: feat->bf16 cvt + degree count + graph bounds --------
__global__ __launch_bounds__(256) void k_prep(const float* __restrict__ feat,
                                              const int* __restrict__ dst,
                                              const int* __restrict__ gid,
                                              unsigned short* __restrict__ fb,
                                              int* __restrict__ deg,
                                              int* __restrict__ start) {
    int g = blockIdx.x * blockDim.x + threadIdx.x;
    int stride = gridDim.x * blockDim.x;
    // cvt: 1.6M chunks of 8 floats
    const float4* f4 = (const float4*)feat;
    for (int i = g; i < (N_NODES * IN_DIM / 8); i += stride) {
        float4 a = f4[i * 2], b = f4[i * 2 + 1];
        ushort8 v;
        v[0] = f2bf(a.x); v[1] = f2bf(a.y); v[2] = f2bf(a.z); v[3] = f2bf(a.w);
        v[4] = f2bf(b.x); v[5] = f2bf(b.y); v[6] = f2bf(b.z); v[7] = f2bf(b.w);
        *(ushort8*)&fb[(size_t)i * 8] = v;
    }
    // degree count
    for (int e = g; e < E_EDGES; e += stride) atomicAdd(&deg[dst[e]], 1);
    // graph segment boundaries (gid sorted)
    for (int n = g; n < N_NODES; n += stride) {
        int b = gid[n];
        if (n == 0) {
            for (int q = 0; q <= b; ++q) start[q] = 0;
        } else {
            int a = gid[n - 1];
            for (int q = a + 1; q <= b; ++q) start[q] = n;
        }
        if (n == N_NODES - 1) {
            for (int q = b + 1; q <= NG; ++q) start[q] = N_NODES;
        }
    }
}

// -------- hierarchical scan: block sums --------
__global__ __launch_bounds__(256) void k_scan1(const int* __restrict__ deg, int* __restrict__ bsum) {
    __shared__ int sh[256];
    int b = blockIdx.x, t = threadIdx.x;
    int n = b * 256 + t;
    sh[t] = (n < N_NODES) ? deg[n] : 0;
    __syncthreads();
    for (int s = 128; s > 0; s >>= 1) {
        if (t < s) sh[t] += sh[t + s];
        __syncthreads();
    }
    if (t == 0) bsum[b] = sh[0];
}

// -------- scan of block sums (exclusive, in place) --------
__global__ __launch_bounds__(512) void k_scan2(int* __restrict__ bsum, int* __restrict__ row_off) {
    __shared__ int sh[512];
    int t = threadIdx.x;
    int v = (t < NBLK) ? bsum[t] : 0;
    sh[t] = v;
    __syncthreads();
    for (int off = 1; off < 512; off <<= 1) {
        int add = (t >= off) ? sh[t - off] : 0;
        __syncthreads();
        sh[t] += add;
        __syncthreads();
    }
    if (t < NBLK) bsum[t] = sh[t] - v;  // exclusive block offset
    if (t == 0) row_off[N_NODES] = E_EDGES;
}

// -------- per-block exclusive scan + offset --------
__global__ __launch_bounds__(256) void k_scan3(const int* __restrict__ deg, const int* __restrict__ bsum,
                                               int* __restrict__ row_off, int* __restrict__ cursor) {
    __shared__ int sh[256];
    int b = blockIdx.x, t = threadIdx.x;
    int n = b * 256 + t;
    int v = (n < N_NODES) ? deg[n] : 0;
    sh[t] = v;
    __syncthreads();
    for (int off = 1; off < 256; off <<= 1) {
        int add = (t >= off) ? sh[t - off] : 0;
        __syncthreads();
        sh[t] += add;
        __syncthreads();
    }
    int ex = bsum[b] + sh[t] - v;
    if (n < N_NODES) { row_off[n] = ex; cursor[n] = ex; }
}

// -------- weight prepack: Wt[n][k] bf16 (aliases dead deg region) --------
__global__ __launch_bounds__(256) void k_prepw(const float* __restrict__ W_self,
                                               const float* __restrict__ W_neigh,
                                               unsigned short* __restrict__ Wt) {
    int n = blockIdx.x, k = threadIdx.x;
    float w = (k < 128) ? W_self[k * HID + n] : W_neigh[(k - 128) * HID + n];
    Wt[n * 256 + k] = f2bf(w);
}

// -------- scatter edges into CSR order --------
__global__ void k_scatter(const int* __restrict__ src, const int* __restrict__ dst,
                          int* __restrict__ cursor, int* __restrict__ sorted_src) {
    int i = blockIdx.x * blockDim.x + threadIdx.x;
    int stride = gridDim.x * blockDim.x;
    for (int e = i; e < E_EDGES; e += stride) {
        int d = dst[e];
        int pos = atomicAdd(&cursor[d], 1);
        sorted_src[pos] = src[e];
    }
}

// -------- mean aggregation (bf16 gather, bf16 out): one wave per node --------
__global__ __launch_bounds__(256) void k_agg(const unsigned short* __restrict__ fb,
                                             const int* __restrict__ row_off,
                                             const int* __restrict__ sorted_src,
                                             unsigned short* __restrict__ hb) {
    int wave = threadIdx.x >> 6;
    int lane = threadIdx.x & 63;
    int n = blockIdx.x * 4 + wave;
    if (n >= N_NODES) return;
    int k0 = __builtin_amdgcn_readfirstlane(row_off[n]);
    int k1 = __builtin_amdgcn_readfirstlane(row_off[n + 1]);
    float ax = 0.f, ay = 0.f;
    int k = k0;
    for (; k + 4 <= k1; k += 4) {
        int s0 = sorted_src[k], s1 = sorted_src[k + 1], s2 = sorted_src[k + 2], s3 = sorted_src[k + 3];
        unsigned u0 = *(const unsigned*)&fb[(size_t)s0 * IN_DIM + lane * 2];
        unsigned u1 = *(const unsigned*)&fb[(size_t)s1 * IN_DIM + lane * 2];
        unsigned u2 = *(const unsigned*)&fb[(size_t)s2 * IN_DIM + lane * 2];
        unsigned u3 = *(const unsigned*)&fb[(size_t)s3 * IN_DIM + lane * 2];
        ax += bf2f(u0 & 0xffff) + bf2f(u1 & 0xffff) + bf2f(u2 & 0xffff) + bf2f(u3 & 0xffff);
        ay += bf2f(u0 >> 16) + bf2f(u1 >> 16) + bf2f(u2 >> 16) + bf2f(u3 >> 16);
    }
    for (; k < k1; ++k) {
        unsigned u0 = *(const unsigned*)&fb[(size_t)sorted_src[k] * IN_DIM + lane * 2];
        ax += bf2f(u0 & 0xffff);
        ay += bf2f(u0 >> 16);
    }
    float inv = 1.f / fmaxf((float)(k1 - k0), 1.f);
    unsigned out = (unsigned)f2bf(ax * inv) | ((unsigned)f2bf(ay * inv) << 16);
    *(unsigned*)&hb[(size_t)n * IN_DIM + lane * 2] = out;
}

// -------- MFMA conv GEMM + relu + BN stats + graph pooling --------
// 1024 threads / 16 waves; wave w owns output cols [w*16, w*16+16), B held in VGPRs.
// Block processes 256 contiguous rows as 4 tiles of 64.
__global__ __launch_bounds__(1024, 4) void k_gemm(const unsigned short* __restrict__ fb,
                                                  const unsigned short* __restrict__ hb,
                                                  const unsigned short* __restrict__ Wt,
                                                  const float* __restrict__ b_conv,
                                                  const int* __restrict__ gid,
                                                  float* __restrict__ colsum,
                                                  float* __restrict__ colsq,
                                                  float* __restrict__ pooled_raw) {
    __shared__ unsigned short A_l[64 * 264];   // 64 rows x 256 k, stride 264 (pad 8)
    __shared__ float pool_l[8][256];
    __shared__ float csum_l[256], csq_l[256];
    __shared__ int gid_s[256];

    int tid = threadIdx.x;
    int lane = tid & 63;
    int wid = tid >> 6;            // 0..15
    int lr15 = lane & 15;
    int lq = lane >> 4;            // 0..3
    int ncol = wid * 16 + lr15;    // this lane's output column
    int n0 = blockIdx.x * 256;

    if (tid < 256) {
        csum_l[tid] = 0.f; csq_l[tid] = 0.f;
        gid_s[tid] = (n0 + tid < N_NODES) ? gid[n0 + tid] : 0x7fffffff;
    }
    ((float*)pool_l)[tid] = 0.f;
    ((float*)pool_l)[1024 + tid] = 0.f;

    // B fragments in registers: 8 k-steps x bf16x8
    bf16x8 bfr[8];
#pragma unroll
    for (int kc = 0; kc < 8; ++kc)
        bfr[kc] = *(const bf16x8*)&Wt[(size_t)ncol * 256 + kc * 32 + lq * 8];
    float bc = b_conv[ncol];
    int g_base = gid[(n0 < N_NODES) ? n0 : (N_NODES - 1)];

    float cs = 0.f, cq = 0.f;

    for (int t = 0; t < 4; ++t) {
        int bn0 = n0 + t * 64;
        __syncthreads();   // init done / previous tile's A reads done
        // stage A tile: 64 rows x 256 k (2048 x 16B chunks, 2 per thread)
#pragma unroll
        for (int i = 0; i < 2; ++i) {
            int idx = i * 1024 + tid;
            int r = idx >> 5;          // 0..63
            int c = idx & 31;          // 16B chunk within row (k = c*8)
            int node = bn0 + r;
            ushort8 v = {0, 0, 0, 0, 0, 0, 0, 0};
            if (node < N_NODES) {
                v = (c < 16) ? *(const ushort8*)&fb[(size_t)node * IN_DIM + c * 8]
                             : *(const ushort8*)&hb[(size_t)node * IN_DIM + (c - 16) * 8];
            }
            *(ushort8*)&A_l[r * 264 + c * 8] = v;
        }
        __syncthreads();

        f32x4 acc[4];
#pragma unroll
        for (int rf = 0; rf < 4; ++rf) acc[rf] = (f32x4)0.f;
#pragma unroll
        for (int kc = 0; kc < 8; ++kc) {
#pragma unroll
            for (int rf = 0; rf < 4; ++rf) {
                bf16x8 a = *(const bf16x8*)&A_l[(rf * 16 + lr15) * 264 + kc * 32 + lq * 8];
                acc[rf] = __builtin_amdgcn_mfma_f32_16x16x32_bf16(a, bfr[kc], acc[rf], 0, 0, 0);
            }
        }

        // epilogue: bias, relu, stats (regs), pooling (run-length -> LDS slots)
        float ps = 0.f;
        int cg = -1;
#pragma unroll
        for (int rf = 0; rf < 4; ++rf) {
#pragma unroll
            for (int j = 0; j < 4; ++j) {
                int lr = rf * 16 + lq * 4 + j;
                int node = bn0 + lr;
                if (node < N_NODES) {
                    int g = gid_s[t * 64 + lr];
                    if (g != cg) {
                        if (cg >= 0 && ps != 0.f) {
                            int slot = cg - g_base;
                            if (slot < 8) atomicAdd(&pool_l[slot][ncol], ps);
                            else          atomicAdd(&pooled_raw[cg * HID + ncol], ps);
                        }
                        ps = 0.f; cg = g;
                    }
                    float v = fmaxf(acc[rf][j] + bc, 0.f);
                    cs += v; cq += v * v; ps += v;
                }
            }
        }
        if (cg >= 0 && ps != 0.f) {
            int slot = cg - g_base;
            if (slot < 8) atomicAdd(&pool_l[slot][ncol], ps);
            else          atomicAdd(&pooled_raw[cg * HID + ncol], ps);
        }
    }

    // block-level reductions -> global
    atomicAdd(&csum_l[ncol], cs);
    atomicAdd(&csq_l[ncol], cq);
    __syncthreads();
    if (tid < 256) {
        atomicAdd(&colsum[tid], csum_l[tid]);
        atomicAdd(&colsq[tid], csq_l[tid]);
    }
#pragma unroll
    for (int i = 0; i < 2; ++i) {
        int idx = i * 1024 + tid;
        int slot = idx >> 8, c = idx & 255;
        int gg = g_base + slot;
        float v = pool_l[slot][c];
        if (gg < NG && v != 0.f) atomicAdd(&pooled_raw[gg * HID + c], v);
    }
}

// -------- finalize conv BN (affine on pooled sums) --------
__global__ void k_head_prep(const float* __restrict__ colsum, const float* __restrict__ colsq,
                            const float* __restrict__ gamma, const float* __restrict__ beta,
                            const int* __restrict__ start, const float* __restrict__ pooled_raw,
                            float* __restrict__ pooled_final) {
    int c = threadIdx.x;
    float mu = colsum[c] * (1.0f / N_NODES);
    float var = colsq[c] * (1.0f / N_NODES) - mu * mu;
    float a = gamma[c] * rsqrtf(var + EPSV);
    float off = beta[c] - a * mu;
    for (int g = 0; g < NG; ++g) {
        float cg = (float)(start[g + 1] - start[g]);
        pooled_final[g * HID + c] = a * pooled_raw[g * HID + c] + cg * off;
    }
}

// -------- lp linear: y = relu(x@W + b), accumulate BN stats --------
__global__ __launch_bounds__(256) void k_lp(const float* __restrict__ x,
                                            const float* __restrict__ W,
                                            const float* __restrict__ b,
                                            float* __restrict__ yrelu,
                                            float* __restrict__ csum,
                                            float* __restrict__ csq) {
    __shared__ float xl[256];
    int g = blockIdx.x, c = threadIdx.x;
    xl[c] = x[g * HID + c];
    __syncthreads();
    float acc = b[c];
#pragma unroll 8
    for (int k = 0; k < HID; ++k) acc = fmaf(xl[k], W[k * HID + c], acc);
    float r = fmaxf(acc, 0.f);
    yrelu[g * HID + c] = r;
    atomicAdd(&csum[c], r);
    atomicAdd(&csq[c], r * r);
}

// -------- apply BN (write p to ws and d_out) --------
__global__ void k_bn(const float* __restrict__ yrelu, const float* __restrict__ csum,
                     const float* __restrict__ csq, const float* __restrict__ gamma,
                     const float* __restrict__ beta, float* __restrict__ out_a,
                     float* __restrict__ out_b) {
    int g = blockIdx.x, c = threadIdx.x;
    float mu = csum[c] * (1.f / NG);
    float var = csq[c] * (1.f / NG) - mu * mu;
    float a = gamma[c] * rsqrtf(var + EPSV);
    float v = (yrelu[g * HID + c] - mu) * a + beta[c];
    out_a[g * HID + c] = v;
    out_b[g * HID + c] = v;
}

// -------- apply BN + log_softmax --------
__global__ __launch_bounds__(256) void k_bnsm(const float* __restrict__ yrelu,
                                              const float* __restrict__ csum,
                                              const float* __restrict__ csq,
                                              const float* __restrict__ gamma,
                                              const float* __restrict__ beta,
                                              float* __restrict__ out) {
    __shared__ float red[256];
    int g = blockIdx.x, c = threadIdx.x;
    float mu = csum[c] * (1.f / NG);
    float var = csq[c] * (1.f / NG) - mu * mu;
    float a = gamma[c] * rsqrtf(var + EPSV);
    float z = (yrelu[g * HID + c] - mu) * a + beta[c];
    red[c] = z;
    __syncthreads();
    for (int s = 128; s > 0; s >>= 1) {
        if (c < s) red[c] = fmaxf(red[c], red[c + s]);
        __syncthreads();
    }
    float m = red[0];
    __syncthreads();
    red[c] = expf(z - m);
    __syncthreads();
    for (int s = 128; s > 0; s >>= 1) {
        if (c < s) red[c] += red[c + s];
        __syncthreads();
    }
    float lse = m + logf(red[0]);
    out[g * HID + c] = z - lse;
}

extern "C" void kernel_launch(void* const* d_in, const int* in_sizes, int n_in,
                              void* d_out, int out_size, void* d_ws, size_t ws_size,
                              hipStream_t stream) {
    const float* feat    = (const float*)d_in[0];
    const float* W_self  = (const float*)d_in[1];
    const float* W_neigh = (const float*)d_in[2];
    const float* b_conv  = (const float*)d_in[3];
    const float* g_conv  = (const float*)d_in[4];
    const float* be_conv = (const float*)d_in[5];
    const float* W_lp    = (const float*)d_in[6];
    const float* b_lp    = (const float*)d_in[7];
    const float* g_lp    = (const float*)d_in[8];
    const float* be_lp   = (const float*)d_in[9];
    const int* src = (const int*)d_in[10];
    const int* dst = (const int*)d_in[11];
    const int* gid = (const int*)d_in[12];

    char* ws = (char*)d_ws;
    int*   deg        = (int*)(ws + OFF_DEG);
    unsigned short* Wt = (unsigned short*)(ws + OFF_WT);   // aliases deg (dead after scan3)
    float* colsum     = (float*)(ws + OFF_CSUM);
    float* colsq      = (float*)(ws + OFF_CSQ);
    float* pooled_raw = (float*)(ws + OFF_POOLR);
    float* csum1      = (float*)(ws + OFF_CSUM1);
    float* csq1       = (float*)(ws + OFF_CSQ1);
    float* csum2      = (float*)(ws + OFF_CSUM2);
    float* csq2       = (float*)(ws + OFF_CSQ2);
    int*   bsum       = (int*)(ws + OFF_BSUM);
    int*   start      = (int*)(ws + OFF_START);
    int*   row_off    = (int*)(ws + OFF_ROWOFF);
    int*   cursor     = (int*)(ws + OFF_CURSOR);
    float* pooled_f   = (float*)(ws + OFF_POOLF);
    float* y1r        = (float*)(ws + OFF_Y1R);
    float* p_buf      = (float*)(ws + OFF_PBUF);
    float* y2r        = (float*)(ws + OFF_Y2R);
    int*   sorted_src = (int*)(ws + OFF_SSRC);
    unsigned short* fb = (unsigned short*)(ws + OFF_FB16);
    unsigned short* hb = (unsigned short*)(ws + OFF_HN16);

    float* out_ls = (float*)d_out;             // [64,256] log_softmax
    float* out_p  = out_ls + NG * HID;         // [64,256] p

    hipMemsetAsync(d_ws, 0, ZERO_BYTES, stream);
    k_prep<<<2048, 256, 0, stream>>>(feat, dst, gid, fb, deg, start);
    k_scan1<<<NBLK, 256, 0, stream>>>(deg, bsum);
    k_scan2<<<1, 512, 0, stream>>>(bsum, row_off);
    k_scan3<<<NBLK, 256, 0, stream>>>(deg, bsum, row_off, cursor);
    k_prepw<<<256, 256, 0, stream>>>(W_self, W_neigh, Wt);   // deg region now dead
    k_scatter<<<1024, 256, 0, stream>>>(src, dst, cursor, sorted_src);
    k_agg<<<25000, 256, 0, stream>>>(fb, row_off, sorted_src, hb);
    k_gemm<<<NBLK, 1024, 0, stream>>>(fb, hb, Wt, b_conv, gid, colsum, colsq, pooled_raw);
    k_head_prep<<<1, 256, 0, stream>>>(colsum, colsq, g_conv, be_conv, start,
                                       pooled_raw, pooled_f);
    k_lp<<<NG, 256, 0, stream>>>(pooled_f, W_lp, b_lp, y1r, csum1, csq1);
    k_bn<<<NG, 256, 0, stream>>>(y1r, csum1, csq1, g_lp, be_lp, p_buf, out_p);
    k_lp<<<NG, 256, 0, stream>>>(p_buf, W_lp, b_lp, y2r, csum2, csq2);
    k_bnsm<<<NG, 256, 0, stream>>>(y2r, csum2, csq2, g_lp, be_lp, out_ls);
}